// Round 10
// baseline (414.778 us; speedup 1.0000x reference)
//
#include <hip/hip_runtime.h>
#include <hip/hip_bf16.h>

typedef __attribute__((ext_vector_type(8))) short short8;
typedef __attribute__((ext_vector_type(4))) float f32x4;
typedef __attribute__((ext_vector_type(4))) unsigned int uint32x4;

__device__ __forceinline__ unsigned short f2bf(float v) {
    __hip_bfloat16 h = __float2bfloat16(v);   // RNE
    return *reinterpret_cast<unsigned short*>(&h);
}
__device__ __forceinline__ float bf2f(unsigned short u) {
    union { unsigned int i; float f; } x;
    x.i = (unsigned int)u << 16;
    return x.f;
}

constexpr int MAXB  = 2048;   // max fine buckets (N/64 = 1563 here)
constexpr int MAXPB = 1792;   // padded slots per bucket (mean 1024, sigma 32 -> 24 sigma)

// ---------------------------------------------------------------------------
// Weight pre-transpose: Wt[(r*H + h)*64 + d] = bf16( r<R ? W[r][d][h]
//                                                        : Wself[d][h] ).
// ---------------------------------------------------------------------------
template<int H>
__global__ __launch_bounds__(256) void transpose_w(
    const float* __restrict__ W, const float* __restrict__ Wself,
    unsigned short* __restrict__ Wt, int R)
{
    int i = blockIdx.x * 256 + threadIdx.x;
    int total = (R + 1) * H * 64;
    if (i >= total) return;
    int d = i & 63;
    int hh = i >> 6;               // r*H + h
    int r = hh / H, h = hh % H;    // H compile-time -> shifts
    float v = (r < R) ? W[((size_t)r * 64 + d) * H + h]
                      : Wself[(size_t)d * H + h];
    Wt[i] = f2bf(v);
}

// ---------------------------------------------------------------------------
// Cast feat fp32 -> bf16 rows. 8 elems/thread.
// ---------------------------------------------------------------------------
__global__ __launch_bounds__(256) void cast_bf16x8(
    const float* __restrict__ in, unsigned short* __restrict__ outp, int n8)
{
    int i = blockIdx.x * 256 + threadIdx.x;
    if (i >= n8) return;
    const float4 a = ((const float4*)in)[(size_t)i * 2];
    const float4 b = ((const float4*)in)[(size_t)i * 2 + 1];
    short8 u;
    u[0] = (short)f2bf(a.x); u[1] = (short)f2bf(a.y);
    u[2] = (short)f2bf(a.z); u[3] = (short)f2bf(a.w);
    u[4] = (short)f2bf(b.x); u[5] = (short)f2bf(b.y);
    u[6] = (short)f2bf(b.z); u[7] = (short)f2bf(b.w);
    *(short8*)&outp[(size_t)i * 8] = u;
}

// ---------------------------------------------------------------------------
// Padded bucket partition (single pass; R8-verified structure).
// Record: (src << 9) | (et << 6) | (dst & 63).  (src < 2^17, et < 8)
// ---------------------------------------------------------------------------
__global__ __launch_bounds__(256) void zero_int(int* __restrict__ p, int n) {
    int i = blockIdx.x * 256 + threadIdx.x;
    if (i < n) p[i] = 0;
}

__global__ __launch_bounds__(256) void partition_pad(
    const int* __restrict__ src, const int* __restrict__ dst,
    const int* __restrict__ et, int* __restrict__ gcnt,
    int* __restrict__ rec, int E, int N, int B, int CH)
{
    __shared__ int cnt[MAXB];
    __shared__ int base[MAXB];
    const int t = threadIdx.x;
    const int e0 = blockIdx.x * CH, e1 = min(E, e0 + CH);

    for (int i = t; i < B; i += 256) cnt[i] = 0;
    __syncthreads();
    for (int e = e0 + t; e < e1; e += 256) atomicAdd(&cnt[dst[e] >> 6], 1);
    __syncthreads();
    for (int i = t; i < B; i += 256) {
        int h = cnt[i];
        base[i] = h ? atomicAdd(&gcnt[i], h) : 0;
        cnt[i] = 0;
    }
    __syncthreads();
    for (int e = e0 + t; e < e1; e += 256) {
        int d = dst[e];
        int b = d >> 6;
        int pos = base[b] + atomicAdd(&cnt[b], 1);
        if (pos < MAXPB)
            rec[(size_t)b * MAXPB + pos] = (src[e] << 9) | (et[e] << 6) | (d & 63);
    }
}

// ---------------------------------------------------------------------------
// Per-bucket 64*R-bin counting sort by (dst-local, rel).
// nrpS/nrpE[b*64R + local*R + r] = range into padded eidx; eidx[pos] = src.
// ---------------------------------------------------------------------------
__global__ __launch_bounds__(256) void bucket_sort9(
    const int* __restrict__ gcnt, const int* __restrict__ rec,
    int* __restrict__ eidx, int* __restrict__ nrpS, int* __restrict__ nrpE,
    int R)
{
    __shared__ int hist[512];
    __shared__ int excl[512];
    __shared__ int cur[512];
    __shared__ int ts[256];
    const int b = blockIdx.x;
    const int tid = threadIdx.x;
    const int NB = 64 * R;                 // <= 512
    const int p0 = b * MAXPB;
    const int ne = min(gcnt[b], MAXPB);

    for (int i = tid; i < NB; i += 256) hist[i] = 0;
    __syncthreads();
    for (int p = tid; p < ne; p += 256) {
        int rv = rec[p0 + p];
        atomicAdd(&hist[(rv & 63) * R + ((rv >> 6) & 7)], 1);
    }
    __syncthreads();
    // block scan of NB bins (PER <= 2 per thread)
    const int PER = (NB + 255) / 256;
    int loc[2] = {0, 0};
    int s = 0;
    for (int j = 0; j < PER; ++j) {
        int i = tid * PER + j;
        loc[j] = (i < NB) ? hist[i] : 0;
        s += loc[j];
    }
    ts[tid] = s;
    __syncthreads();
    for (int off = 1; off < 256; off <<= 1) {
        int x = (tid >= off) ? ts[tid - off] : 0;
        __syncthreads();
        ts[tid] += x;
        __syncthreads();
    }
    int run = ts[tid] - s;
    for (int j = 0; j < PER; ++j) {
        int i = tid * PER + j;
        if (i < NB) excl[i] = run;
        run += loc[j];
    }
    __syncthreads();
    for (int i = tid; i < NB; i += 256) {
        cur[i] = excl[i];
        nrpS[(size_t)b * NB + i] = p0 + excl[i];
        nrpE[(size_t)b * NB + i] = p0 + excl[i] + hist[i];
    }
    __syncthreads();
    for (int p = tid; p < ne; p += 256) {
        int rv = rec[p0 + p];
        int bin = (rv & 63) * R + ((rv >> 6) & 7);
        int pos = p0 + atomicAdd(&cur[bin], 1);
        eidx[pos] = rv >> 9;   // src
    }
}

// ---------------------------------------------------------------------------
// Register-fused aggregate -> MFMA layer (R9 structure + R10 MLP fix).
// Block = 1 bucket (64 dst), 4 waves x 16 nodes. Lane quad*16+m owns node m's
// cols [quad*8,+8) and [32+quad*8,+8) == verified MFMA B-fragment layout.
// R10: per-(node,rel) edge walk is 4-DEEP BATCHED -- the 4 src indices are
// prefetched together (contiguous, clamped in-bounds), then all 8 row loads
// issue before any accumulate: breaks the eidx->row serial chain that held
// R9 to 803 GB/s. Rel loop compile-time unrolled (RT=8) so the scheduler
// overlaps rel r+1's index loads with rel r's accumulate tail.
// ---------------------------------------------------------------------------
template<int HOUT, bool BF16OUT, int RT>
__global__ __launch_bounds__(256) void fused_mfma(
    const unsigned short* __restrict__ inb,   // bf16 rows [N][64]
    const unsigned short* __restrict__ Wt,    // [(R+1)*HOUT][64] bf16
    const float* __restrict__ bias,           // [HOUT]
    const int* __restrict__ nrpS, const int* __restrict__ nrpE,
    const int* __restrict__ eidx,             // src, (bucket,node,rel)-sorted
    void* __restrict__ outp,
    int N, int Rrt)
{
    constexpr int NT = HOUT / 16;             // 4 (H=64) or 2 (H=32)
    constexpr int CPB = 72;                   // bf16 stage stride (144B rows, 2-way)
    alignas(16) __shared__ float Csf[64 * 36];  // 9216B stage
    const int R = RT ? RT : Rrt;
    const int tid = threadIdx.x, b = blockIdx.x;
    const int w = tid >> 6, lane = tid & 63;
    const int m = lane & 15, quad = lane >> 4;
    const int nl = w * 16 + m;                // node local (0..63)
    const int node = b * 64 + nl;
    const int NB = 64 * R;
    const unsigned int* in32 = (const unsigned int*)inb;

    f32x4 acc[NT];
    #pragma unroll
    for (int nt = 0; nt < NT; ++nt) acc[nt] = (f32x4){0.f, 0.f, 0.f, 0.f};

    #pragma unroll
    for (int r = 0; r < R; ++r) {
        const int bin = b * NB + nl * R + r;
        int p = nrpS[bin];
        const int pe = nrpE[bin];

        float a0[8] = {0.f,0.f,0.f,0.f,0.f,0.f,0.f,0.f};
        float a1[8] = {0.f,0.f,0.f,0.f,0.f,0.f,0.f,0.f};

        while (p < pe) {
            // clamped 4-deep index prefetch (always in-bounds: pe > p here)
            int i1 = min(p + 1, pe - 1);
            int i2 = min(p + 2, pe - 1);
            int i3 = min(p + 3, pe - 1);
            int s0 = eidx[p], s1 = eidx[i1], s2 = eidx[i2], s3 = eidx[i3];
            // all 8 row loads issue together (4 edges x lo/hi 16B)
            uint32x4 lo0 = *(const uint32x4*)&in32[(size_t)s0 * 32 + quad * 4];
            uint32x4 hi0 = *(const uint32x4*)&in32[(size_t)s0 * 32 + 16 + quad * 4];
            uint32x4 lo1 = *(const uint32x4*)&in32[(size_t)s1 * 32 + quad * 4];
            uint32x4 hi1 = *(const uint32x4*)&in32[(size_t)s1 * 32 + 16 + quad * 4];
            uint32x4 lo2 = *(const uint32x4*)&in32[(size_t)s2 * 32 + quad * 4];
            uint32x4 hi2 = *(const uint32x4*)&in32[(size_t)s2 * 32 + 16 + quad * 4];
            uint32x4 lo3 = *(const uint32x4*)&in32[(size_t)s3 * 32 + quad * 4];
            uint32x4 hi3 = *(const uint32x4*)&in32[(size_t)s3 * 32 + 16 + quad * 4];

            #pragma unroll
            for (int j = 0; j < 4; ++j) {
                a0[2*j]   += bf2f((unsigned short)(lo0[j] & 0xffff));
                a0[2*j+1] += bf2f((unsigned short)(lo0[j] >> 16));
                a1[2*j]   += bf2f((unsigned short)(hi0[j] & 0xffff));
                a1[2*j+1] += bf2f((unsigned short)(hi0[j] >> 16));
            }
            if (p + 1 < pe) {
                #pragma unroll
                for (int j = 0; j < 4; ++j) {
                    a0[2*j]   += bf2f((unsigned short)(lo1[j] & 0xffff));
                    a0[2*j+1] += bf2f((unsigned short)(lo1[j] >> 16));
                    a1[2*j]   += bf2f((unsigned short)(hi1[j] & 0xffff));
                    a1[2*j+1] += bf2f((unsigned short)(hi1[j] >> 16));
                }
            }
            if (p + 2 < pe) {
                #pragma unroll
                for (int j = 0; j < 4; ++j) {
                    a0[2*j]   += bf2f((unsigned short)(lo2[j] & 0xffff));
                    a0[2*j+1] += bf2f((unsigned short)(lo2[j] >> 16));
                    a1[2*j]   += bf2f((unsigned short)(hi2[j] & 0xffff));
                    a1[2*j+1] += bf2f((unsigned short)(hi2[j] >> 16));
                }
            }
            if (p + 3 < pe) {
                #pragma unroll
                for (int j = 0; j < 4; ++j) {
                    a0[2*j]   += bf2f((unsigned short)(lo3[j] & 0xffff));
                    a0[2*j+1] += bf2f((unsigned short)(lo3[j] >> 16));
                    a1[2*j]   += bf2f((unsigned short)(hi3[j] & 0xffff));
                    a1[2*j+1] += bf2f((unsigned short)(hi3[j] >> 16));
                }
            }
            p += 4;
        }

        short8 f0, f1;                        // aggregate == B-fragment layout
        #pragma unroll
        for (int j = 0; j < 8; ++j) { f0[j] = (short)f2bf(a0[j]); f1[j] = (short)f2bf(a1[j]); }

        #pragma unroll
        for (int nt = 0; nt < NT; ++nt) {
            const short8 wf0 = *(const short8*)&Wt[((size_t)(r * HOUT + nt * 16 + m)) * 64 + quad * 8];
            const short8 wf1 = *(const short8*)&Wt[((size_t)(r * HOUT + nt * 16 + m)) * 64 + 32 + quad * 8];
            acc[nt] = __builtin_amdgcn_mfma_f32_16x16x32_bf16(wf0, f0, acc[nt], 0, 0, 0);
            acc[nt] = __builtin_amdgcn_mfma_f32_16x16x32_bf16(wf1, f1, acc[nt], 0, 0, 0);
        }
    }

    // self term: node's own row is already bf16 in memory == fragment directly
    short8 se0 = {}, se1 = {};
    if (node < N) {
        se0 = *(const short8*)&inb[(size_t)node * 64 + quad * 8];
        se1 = *(const short8*)&inb[(size_t)node * 64 + 32 + quad * 8];
    }
    #pragma unroll
    for (int nt = 0; nt < NT; ++nt) {
        const short8 wsf0 = *(const short8*)&Wt[((size_t)(R * HOUT + nt * 16 + m)) * 64 + quad * 8];
        const short8 wsf1 = *(const short8*)&Wt[((size_t)(R * HOUT + nt * 16 + m)) * 64 + 32 + quad * 8];
        acc[nt] = __builtin_amdgcn_mfma_f32_16x16x32_bf16(wsf0, se0, acc[nt], 0, 0, 0);
        acc[nt] = __builtin_amdgcn_mfma_f32_16x16x32_bf16(wsf1, se1, acc[nt], 0, 0, 0);
    }

    // epilogue: bias (+relu for layer1), stage, coalesced 16B writes.
    // D layout (verified): reg i -> h-col = nt*16 + quad*4 + i; lane&15 -> node.
    if constexpr (BF16OUT) {
        unsigned short* Cb = (unsigned short*)Csf;
        #pragma unroll
        for (int nt = 0; nt < NT; ++nt) {
            int col = nt * 16 + quad * 4;
            const float4 bv = *(const float4*)&bias[col];
            ushort4 u;
            u.x = f2bf(fmaxf(acc[nt][0] + bv.x, 0.f));
            u.y = f2bf(fmaxf(acc[nt][1] + bv.y, 0.f));
            u.z = f2bf(fmaxf(acc[nt][2] + bv.z, 0.f));
            u.w = f2bf(fmaxf(acc[nt][3] + bv.w, 0.f));
            *(ushort4*)&Cb[nl * CPB + col] = u;
        }
        __syncthreads();
        unsigned short* outu = (unsigned short*)outp;
        #pragma unroll
        for (int it = 0; it < 2; ++it) {
            int i = tid + it * 256;           // 64 rows x 8 chunks of 16B
            int rw = i >> 3, ch = i & 7;
            int gn = b * 64 + rw;
            if (gn < N) {
                uint32x4 v = *(const uint32x4*)&Cb[rw * CPB + ch * 8];
                *(uint32x4*)&outu[(size_t)gn * 64 + ch * 8] = v;
            }
        }
    } else {
        float* Cf = Csf;
        #pragma unroll
        for (int nt = 0; nt < NT; ++nt) {
            int col = nt * 16 + quad * 4;
            const float4 bv = *(const float4*)&bias[col];
            float4 o = make_float4(acc[nt][0] + bv.x, acc[nt][1] + bv.y,
                                   acc[nt][2] + bv.z, acc[nt][3] + bv.w);
            *(float4*)&Cf[nl * 36 + col] = o;
        }
        __syncthreads();
        float* outf = (float*)outp;
        #pragma unroll
        for (int it = 0; it < 2; ++it) {
            int i = tid + it * 256;           // 64 rows x 8 float4
            int rw = i >> 3, ch = i & 7;
            int gn = b * 64 + rw;
            if (gn < N) {
                float4 v = *(const float4*)&Cf[rw * 36 + ch * 4];
                *(float4*)&outf[(size_t)gn * 32 + ch * 4] = v;
            }
        }
    }
}

extern "C" void kernel_launch(void* const* d_in, const int* in_sizes, int n_in,
                              void* d_out, int out_size, void* d_ws, size_t ws_size,
                              hipStream_t stream)
{
    const float* feat = (const float*)d_in[0];
    const int*   src  = (const int*)d_in[1];
    const int*   dst  = (const int*)d_in[2];
    const int*   et   = (const int*)d_in[3];
    const float* W1   = (const float*)d_in[4];
    const float* Ws1  = (const float*)d_in[5];
    const float* b1   = (const float*)d_in[6];
    const float* W2   = (const float*)d_in[7];
    const float* Ws2  = (const float*)d_in[8];
    const float* b2   = (const float*)d_in[9];
    float* out = (float*)d_out;

    const int N = in_sizes[0] / 64;           // 100000
    const int E = in_sizes[1];                // 1600000
    const int R = in_sizes[4] / (64 * 64);    // 8
    const int B = (N + 63) / 64;              // 1563 fine buckets

    // Workspace layout
    unsigned short* fstage = (unsigned short*)d_ws;            // [N][64] bf16 feat
    unsigned short* h1     = fstage + (size_t)N * 64;          // [N][64] bf16 relu(h1)
    unsigned short* Wt1    = h1 + (size_t)N * 64;              // [(R+1)*64*64]
    unsigned short* Wt2    = Wt1 + (size_t)(R + 1) * 64 * 64;  // [(R+1)*32*64]
    int* gcnt = (int*)(Wt2 + (size_t)(R + 1) * 32 * 64);       // [B]
    int* nrpS = gcnt + B;                                      // [B*64*R]
    int* nrpE = nrpS + (size_t)B * 64 * R;                     // [B*64*R]
    int* rec  = nrpE + (size_t)B * 64 * R;                     // [B*MAXPB]
    int* eidx = rec + (size_t)B * MAXPB;                       // [B*MAXPB]

    const dim3 blk(256);
    const int P  = 512;                       // partition blocks
    const int CH = (E + P - 1) / P;           // 3125 edges per block
    const int n8 = N * 64 / 8;                // 800000

    // ---- Weight pre-transpose + input bf16 cast ----
    transpose_w<64><<<((R + 1) * 64 * 64 + 255) / 256, blk, 0, stream>>>(W1, Ws1, Wt1, R);
    transpose_w<32><<<((R + 1) * 32 * 64 + 255) / 256, blk, 0, stream>>>(W2, Ws2, Wt2, R);
    cast_bf16x8<<<(n8 + 255) / 256, blk, 0, stream>>>(feat, fstage, n8);

    // ---- Build per-(node,rel) CSR (padded buckets) ----
    zero_int<<<(B + 255) / 256, blk, 0, stream>>>(gcnt, B);
    partition_pad<<<P, blk, 0, stream>>>(src, dst, et, gcnt, rec, E, N, B, CH);
    bucket_sort9<<<B, blk, 0, stream>>>(gcnt, rec, eidx, nrpS, nrpE, R);

    // ---- Layer 1: fused aggregate+MFMA -> h1 = relu(.) bf16 ----
    if (R == 8)
        fused_mfma<64, true, 8><<<B, blk, 0, stream>>>(fstage, Wt1, b1, nrpS, nrpE, eidx, h1, N, R);
    else
        fused_mfma<64, true, 0><<<B, blk, 0, stream>>>(fstage, Wt1, b1, nrpS, nrpE, eidx, h1, N, R);

    // ---- Layer 2: fused aggregate+MFMA -> out fp32 ----
    if (R == 8)
        fused_mfma<32, false, 8><<<B, blk, 0, stream>>>(h1, Wt2, b2, nrpS, nrpE, eidx, out, N, R);
    else
        fused_mfma<32, false, 0><<<B, blk, 0, stream>>>(h1, Wt2, b2, nrpS, nrpE, eidx, out, N, R);
}

// Round 11
// 337.169 us; speedup vs baseline: 1.2302x; 1.2302x over previous
//
#include <hip/hip_runtime.h>
#include <hip/hip_bf16.h>

typedef __attribute__((ext_vector_type(8))) short short8;
typedef __attribute__((ext_vector_type(4))) float f32x4;

__device__ __forceinline__ unsigned short f2bf(float v) {
    __hip_bfloat16 h = __float2bfloat16(v);   // RNE
    return *reinterpret_cast<unsigned short*>(&h);
}
__device__ __forceinline__ float bf2f(unsigned short u) {
    union { unsigned int i; float f; } x;
    x.i = (unsigned int)u << 16;
    return x.f;
}
__device__ __forceinline__ void acc4(float& s0, float& s1, float& s2, float& s3, uint2 v) {
    s0 += bf2f((unsigned short)(v.x & 0xffff));
    s1 += bf2f((unsigned short)(v.x >> 16));
    s2 += bf2f((unsigned short)(v.y & 0xffff));
    s3 += bf2f((unsigned short)(v.y >> 16));
}

// Cross-wave LDS barrier WITHOUT the vmcnt(0) drain __syncthreads carries.
__device__ __forceinline__ void lds_barrier() {
    asm volatile("s_waitcnt lgkmcnt(0)" ::: "memory");
    __builtin_amdgcn_s_barrier();
    asm volatile("" ::: "memory");
}

constexpr int MAXB  = 2048;   // max fine buckets (N/64 = 1563 here)
constexpr int MAXPB = 1792;   // padded slots per bucket (mean 1024, sigma 32 -> 24 sigma)

// ---------------------------------------------------------------------------
// Weight pre-transpose: Wt[(r*H + h)*64 + d] = bf16( r<R ? W[r][d][h]
//                                                        : Wself[d][h] ).
// ---------------------------------------------------------------------------
template<int H>
__global__ __launch_bounds__(256) void transpose_w(
    const float* __restrict__ W, const float* __restrict__ Wself,
    unsigned short* __restrict__ Wt, int R)
{
    int i = blockIdx.x * 256 + threadIdx.x;
    int total = (R + 1) * H * 64;
    if (i >= total) return;
    int d = i & 63;
    int hh = i >> 6;               // r*H + h
    int r = hh / H, h = hh % H;    // H compile-time -> shifts
    float v = (r < R) ? W[((size_t)r * 64 + d) * H + h]
                      : Wself[(size_t)d * H + h];
    Wt[i] = f2bf(v);
}

// ---------------------------------------------------------------------------
// MFMA relation GEMM (operand-swapped, depth-2 W prefetch). R4/R8-verified.
// ---------------------------------------------------------------------------
template<int H, int RT, bool ABF, bool SBF>
__global__ __launch_bounds__(512) void gemm_rel_mfma(
    const void* __restrict__ Av, const unsigned short* __restrict__ Wt,
    const float* __restrict__ bias,
    unsigned short* __restrict__ C, void* __restrict__ Cselfv,
    int N, int Rrt, int relu)
{
    constexpr int AS = 72;   // 144 B/row = 36 words = 4 mod 32 -> 2-way (free)
    constexpr int CPB = (H == 64) ? 72 : 40;   // bf16 staging stride (16B-aligned rows)
    __shared__ unsigned short As[64 * AS];
    alignas(16) __shared__ float Csf[2][64 * 36];  // dbuf staging (bf16/fp32 union)
    const int R = RT ? RT : Rrt;
    const int tid = threadIdx.x;
    const int n0 = blockIdx.x * 64;

    if constexpr (ABF) {
        const unsigned short* A = (const unsigned short*)Av;
        int n = tid >> 3, d8 = (tid & 7) * 8;
        int gn = n0 + n;
        short8 u = {};
        if (gn < N) u = *(const short8*)&A[(size_t)gn * 64 + d8];
        if (relu) {
            #pragma unroll
            for (int j = 0; j < 8; ++j) {
                unsigned short x = (unsigned short)u[j];
                u[j] = (short)((x & 0x8000) ? 0 : x);   // bf16 relu = sign test
            }
        }
        *(short8*)&As[n * AS + d8] = u;
    } else {
        const float* A = (const float*)Av;
        #pragma unroll
        for (int i = 0; i < 2; ++i) {
            int lin = tid + i * 512;
            int n = lin >> 4;
            int d4 = (lin & 15) * 4;
            int gn = n0 + n;
            float4 v = make_float4(0.f, 0.f, 0.f, 0.f);
            if (gn < N) v = *(const float4*)&A[(size_t)gn * 64 + d4];
            if (relu) {
                v.x = fmaxf(v.x, 0.f); v.y = fmaxf(v.y, 0.f);
                v.z = fmaxf(v.z, 0.f); v.w = fmaxf(v.w, 0.f);
            }
            ushort4 u;
            u.x = f2bf(v.x); u.y = f2bf(v.y); u.z = f2bf(v.z); u.w = f2bf(v.w);
            *(ushort4*)&As[n * AS + d4] = u;
        }
    }

    const int w = tid >> 6, lane = tid & 63;
    const int m = lane & 15, quad = lane >> 4;
    const int wt = w & 3;        // node sub-tile (16 nodes)
    const int half = w >> 2;     // column half (H/2 cols)

    lds_barrier();

    short8 afrag[2];
    afrag[0] = *(const short8*)&As[(wt * 16 + m) * AS + 0 * 32 + quad * 8];
    afrag[1] = *(const short8*)&As[(wt * 16 + m) * AS + 1 * 32 + quad * 8];

    constexpr int NT = H / 32;   // col-tiles per wave (64->2, 32->1)

    auto wptr = [&](int r, int nt, int kc) {
        int colbase = half * (H / 2) + nt * 16;
        return (const short8*)&Wt[((size_t)(r * H + colbase + m)) * 64 + kc * 32 + quad * 8];
    };

    short8 wf0[NT][2], wf1[NT][2];
    #pragma unroll
    for (int nt = 0; nt < NT; ++nt) { wf0[nt][0] = *wptr(0, nt, 0); wf0[nt][1] = *wptr(0, nt, 1); }
    #pragma unroll
    for (int nt = 0; nt < NT; ++nt) { wf1[nt][0] = *wptr(1, nt, 0); wf1[nt][1] = *wptr(1, nt, 1); }

    #pragma unroll
    for (int r = 0; r <= R; ++r) {
        short8 wn[NT][2];
        if (r + 2 <= R) {
            #pragma unroll
            for (int nt = 0; nt < NT; ++nt) {
                wn[nt][0] = *wptr(r + 2, nt, 0);
                wn[nt][1] = *wptr(r + 2, nt, 1);
            }
        }

        f32x4 acc[NT];
        #pragma unroll
        for (int nt = 0; nt < NT; ++nt) {
            acc[nt] = (f32x4){0.f, 0.f, 0.f, 0.f};
            acc[nt] = __builtin_amdgcn_mfma_f32_16x16x32_bf16(wf0[nt][0], afrag[0], acc[nt], 0, 0, 0);
            acc[nt] = __builtin_amdgcn_mfma_f32_16x16x32_bf16(wf0[nt][1], afrag[1], acc[nt], 0, 0, 0);
        }

        // ---- stage into Csf[r&1] ----
        unsigned short* Cb = (unsigned short*)Csf[r & 1];
        float* Cf = Csf[r & 1];
        if (r < R) {
            #pragma unroll
            for (int nt = 0; nt < NT; ++nt) {
                int col = half * (H / 2) + nt * 16 + quad * 4;
                ushort4 u;
                u.x = f2bf(acc[nt][0]); u.y = f2bf(acc[nt][1]);
                u.z = f2bf(acc[nt][2]); u.w = f2bf(acc[nt][3]);
                *(ushort4*)&Cb[(wt * 16 + m) * CPB + col] = u;
            }
        } else if constexpr (SBF) {
            #pragma unroll
            for (int nt = 0; nt < NT; ++nt) {
                int col = half * (H / 2) + nt * 16 + quad * 4;
                const float4 bv = *(const float4*)&bias[col];
                ushort4 u;
                u.x = f2bf(acc[nt][0] + bv.x); u.y = f2bf(acc[nt][1] + bv.y);
                u.z = f2bf(acc[nt][2] + bv.z); u.w = f2bf(acc[nt][3] + bv.w);
                *(ushort4*)&Cb[(wt * 16 + m) * CPB + col] = u;
            }
        } else {
            #pragma unroll
            for (int nt = 0; nt < NT; ++nt) {
                int col = half * (H / 2) + nt * 16 + quad * 4;
                const float4 bv = *(const float4*)&bias[col];
                float4 o = make_float4(acc[nt][0] + bv.x, acc[nt][1] + bv.y,
                                       acc[nt][2] + bv.z, acc[nt][3] + bv.w);
                *(float4*)&Cf[(wt * 16 + m) * 36 + col] = o;
            }
        }

        lds_barrier();   // lgkm-only: stage(r) visible; r-1 readout reads done

        // ---- coalesced readout from Csf[r&1] ----
        if (r < R) {
            if (H == 64) {
                int rw = tid >> 3, ch = tid & 7;      // 64 rows x 8 chunks of 16B
                int gn = n0 + rw;
                if (gn < N) {
                    uint4 v = *(const uint4*)&Cb[rw * CPB + ch * 8];
                    *(uint4*)&C[((size_t)r * N + gn) * H + ch * 8] = v;
                }
            } else {
                if (tid < 256) {
                    int rw = tid >> 2, ch = tid & 3;  // 64 rows x 4 chunks of 16B
                    int gn = n0 + rw;
                    if (gn < N) {
                        uint4 v = *(const uint4*)&Cb[rw * CPB + ch * 8];
                        *(uint4*)&C[((size_t)r * N + gn) * H + ch * 8] = v;
                    }
                }
            }
        } else if constexpr (SBF) {
            unsigned short* Cs = (unsigned short*)Cselfv;
            int rw = tid >> 3, ch = tid & 7;
            int gn = n0 + rw;
            if (gn < N) {
                uint4 v = *(const uint4*)&Cb[rw * CPB + ch * 8];
                *(uint4*)&Cs[(size_t)gn * H + ch * 8] = v;
            }
        } else {
            float* outf = (float*)Cselfv;
            int rw = tid >> 3, ch = tid & 7;          // 64 rows x 8 float4
            int gn = n0 + rw;
            if (gn < N) {
                float4 v = *(const float4*)&Cf[rw * 36 + ch * 4];
                *(float4*)&outf[(size_t)gn * 32 + ch * 4] = v;
            }
        }

        #pragma unroll
        for (int nt = 0; nt < NT; ++nt) {
            wf0[nt][0] = wf1[nt][0]; wf0[nt][1] = wf1[nt][1];
            wf1[nt][0] = wn[nt][0];  wf1[nt][1] = wn[nt][1];
        }
    }
}

// ---------------------------------------------------------------------------
// Padded bucket partition (single pass over edges; R8-verified).
// Record: (et*N + src) << 6 | (dst & 63).
// ---------------------------------------------------------------------------
__global__ __launch_bounds__(256) void zero_int(int* __restrict__ p, int n) {
    int i = blockIdx.x * 256 + threadIdx.x;
    if (i < n) p[i] = 0;
}

__global__ __launch_bounds__(256) void partition_pad(
    const int* __restrict__ src, const int* __restrict__ dst,
    const int* __restrict__ et, int* __restrict__ gcnt,
    int* __restrict__ rec, int E, int N, int B, int CH)
{
    __shared__ int cnt[MAXB];
    __shared__ int base[MAXB];
    const int t = threadIdx.x;
    const int e0 = blockIdx.x * CH, e1 = min(E, e0 + CH);

    for (int i = t; i < B; i += 256) cnt[i] = 0;
    __syncthreads();
    for (int e = e0 + t; e < e1; e += 256) atomicAdd(&cnt[dst[e] >> 6], 1);
    __syncthreads();
    for (int i = t; i < B; i += 256) {
        int h = cnt[i];
        base[i] = h ? atomicAdd(&gcnt[i], h) : 0;
        cnt[i] = 0;
    }
    __syncthreads();
    for (int e = e0 + t; e < e1; e += 256) {
        int d = dst[e];
        int b = d >> 6;
        int pos = base[b] + atomicAdd(&cnt[b], 1);
        if (pos < MAXPB)
            rec[(size_t)b * MAXPB + pos] = ((et[e] * N + src[e]) << 6) | (d & 63);
    }
}

// ---------------------------------------------------------------------------
// Per-bucket counting sort -> per-node ranges rs/re into padded eidx.
// ---------------------------------------------------------------------------
__global__ __launch_bounds__(256) void bucket_sort(
    const int* __restrict__ gcnt, const int* __restrict__ rec,
    int* __restrict__ eidx, int* __restrict__ rs, int* __restrict__ re_,
    int N)
{
    __shared__ int hist[64];
    __shared__ int excl[64];
    __shared__ int cur[64];
    const int b = blockIdx.x;
    const int tid = threadIdx.x;
    const int p0 = b * MAXPB;
    const int ne = min(gcnt[b], MAXPB);

    if (tid < 64) hist[tid] = 0;
    __syncthreads();
    for (int p = tid; p < ne; p += 256)
        atomicAdd(&hist[rec[p0 + p] & 63], 1);
    __syncthreads();
    if (tid == 0) {
        int run = 0;
        #pragma unroll
        for (int i = 0; i < 64; ++i) { excl[i] = run; run += hist[i]; }
    }
    __syncthreads();
    if (tid < 64) {
        cur[tid] = excl[tid];
        int n = b * 64 + tid;
        if (n < N) {
            rs[n]  = p0 + excl[tid];
            re_[n] = p0 + excl[tid] + hist[tid];
        }
    }
    __syncthreads();
    for (int p = tid; p < ne; p += 256) {
        int rv = rec[p0 + p];
        int pos = p0 + atomicAdd(&cur[rv & 63], 1);
        eidx[pos] = rv >> 6;   // et*N + src
    }
}

// ---------------------------------------------------------------------------
// agg64 v2: one wave per dst node; 4 groups of 16 lanes, each group loads a
// full 128B row via uint2 (8B/lane) -> 4 edges concurrently per wave, 4-deep
// unroll (32B/lane in flight). Cross-group combine via shfl_xor(16,32);
// group 0 does the coalesced read-modify-write of h1 (bf16 packed).
// ---------------------------------------------------------------------------
__global__ __launch_bounds__(256) void agg_csr64(
    const unsigned int* __restrict__ hw32, const int* __restrict__ rs,
    const int* __restrict__ re_, const int* __restrict__ eidx,
    unsigned int* __restrict__ out32, int N)
{
    const int d = blockIdx.x * 4 + (threadIdx.x >> 6);
    const int lane = threadIdx.x & 63;
    if (d >= N) return;
    const int g = lane >> 4;      // edge group 0..3
    const int c = lane & 15;      // uint2 col (4 bf16 cols: 4c..4c+3)
    const int p0 = rs[d], p1 = re_[d];
    float s0 = 0.f, s1 = 0.f, s2 = 0.f, s3 = 0.f;
    int p = p0 + g;
    for (; p + 12 < p1; p += 16) {
        uint2 v0 = *(const uint2*)&hw32[(size_t)eidx[p]      * 32 + 2 * c];
        uint2 v1 = *(const uint2*)&hw32[(size_t)eidx[p + 4]  * 32 + 2 * c];
        uint2 v2 = *(const uint2*)&hw32[(size_t)eidx[p + 8]  * 32 + 2 * c];
        uint2 v3 = *(const uint2*)&hw32[(size_t)eidx[p + 12] * 32 + 2 * c];
        acc4(s0, s1, s2, s3, v0);
        acc4(s0, s1, s2, s3, v1);
        acc4(s0, s1, s2, s3, v2);
        acc4(s0, s1, s2, s3, v3);
    }
    for (; p < p1; p += 4) {
        uint2 v = *(const uint2*)&hw32[(size_t)eidx[p] * 32 + 2 * c];
        acc4(s0, s1, s2, s3, v);
    }
    s0 += __shfl_xor(s0, 16, 64); s1 += __shfl_xor(s1, 16, 64);
    s2 += __shfl_xor(s2, 16, 64); s3 += __shfl_xor(s3, 16, 64);
    s0 += __shfl_xor(s0, 32, 64); s1 += __shfl_xor(s1, 32, 64);
    s2 += __shfl_xor(s2, 32, 64); s3 += __shfl_xor(s3, 32, 64);
    if (g == 0) {
        uint2 cur = *(const uint2*)&out32[(size_t)d * 32 + 2 * c];
        float o0 = s0 + bf2f((unsigned short)(cur.x & 0xffff));
        float o1 = s1 + bf2f((unsigned short)(cur.x >> 16));
        float o2 = s2 + bf2f((unsigned short)(cur.y & 0xffff));
        float o3 = s3 + bf2f((unsigned short)(cur.y >> 16));
        uint2 o;
        o.x = (unsigned int)f2bf(o0) | ((unsigned int)f2bf(o1) << 16);
        o.y = (unsigned int)f2bf(o2) | ((unsigned int)f2bf(o3) << 16);
        *(uint2*)&out32[(size_t)d * 32 + 2 * c] = o;
    }
}

// ---------------------------------------------------------------------------
// agg32 v2: 32 lanes per dst node; 4 groups of 8 lanes, uint2 row loads
// (64B row), 4-deep unroll; combine via shfl_xor(8,16); group 0 writes
// float4 read-modify-write of out (fp32).
// ---------------------------------------------------------------------------
__global__ __launch_bounds__(256) void agg_csr32(
    const unsigned int* __restrict__ hw32, const int* __restrict__ rs,
    const int* __restrict__ re_, const int* __restrict__ eidx,
    float* __restrict__ out, int N)
{
    const int d = blockIdx.x * 8 + (threadIdx.x >> 5);
    const int l = threadIdx.x & 31;
    if (d >= N) return;
    const int g = l >> 3;         // edge group 0..3
    const int c = l & 7;          // uint2 col (4 bf16 cols of 32)
    const int p0 = rs[d], p1 = re_[d];
    float s0 = 0.f, s1 = 0.f, s2 = 0.f, s3 = 0.f;
    int p = p0 + g;
    for (; p + 12 < p1; p += 16) {
        uint2 v0 = *(const uint2*)&hw32[(size_t)eidx[p]      * 16 + 2 * c];
        uint2 v1 = *(const uint2*)&hw32[(size_t)eidx[p + 4]  * 16 + 2 * c];
        uint2 v2 = *(const uint2*)&hw32[(size_t)eidx[p + 8]  * 16 + 2 * c];
        uint2 v3 = *(const uint2*)&hw32[(size_t)eidx[p + 12] * 16 + 2 * c];
        acc4(s0, s1, s2, s3, v0);
        acc4(s0, s1, s2, s3, v1);
        acc4(s0, s1, s2, s3, v2);
        acc4(s0, s1, s2, s3, v3);
    }
    for (; p < p1; p += 4) {
        uint2 v = *(const uint2*)&hw32[(size_t)eidx[p] * 16 + 2 * c];
        acc4(s0, s1, s2, s3, v);
    }
    s0 += __shfl_xor(s0, 8, 64);  s1 += __shfl_xor(s1, 8, 64);
    s2 += __shfl_xor(s2, 8, 64);  s3 += __shfl_xor(s3, 8, 64);
    s0 += __shfl_xor(s0, 16, 64); s1 += __shfl_xor(s1, 16, 64);
    s2 += __shfl_xor(s2, 16, 64); s3 += __shfl_xor(s3, 16, 64);
    if (g == 0) {
        float4 cur = *(const float4*)&out[(size_t)d * 32 + 4 * c];
        float4 o = make_float4(cur.x + s0, cur.y + s1, cur.z + s2, cur.w + s3);
        *(float4*)&out[(size_t)d * 32 + 4 * c] = o;
    }
}

extern "C" void kernel_launch(void* const* d_in, const int* in_sizes, int n_in,
                              void* d_out, int out_size, void* d_ws, size_t ws_size,
                              hipStream_t stream)
{
    const float* feat = (const float*)d_in[0];
    const int*   src  = (const int*)d_in[1];
    const int*   dst  = (const int*)d_in[2];
    const int*   et   = (const int*)d_in[3];
    const float* W1   = (const float*)d_in[4];
    const float* Ws1  = (const float*)d_in[5];
    const float* b1   = (const float*)d_in[6];
    const float* W2   = (const float*)d_in[7];
    const float* Ws2  = (const float*)d_in[8];
    const float* b2   = (const float*)d_in[9];
    float* out = (float*)d_out;

    const int N = in_sizes[0] / 64;           // 100000
    const int E = in_sizes[1];                // 1600000
    const int R = in_sizes[4] / (64 * 64);    // 8
    const int B = (N + 63) / 64;              // 1563 fine buckets

    // Workspace layout
    unsigned short* hW  = (unsigned short*)d_ws;           // [R][N][64] bf16 (reused [R][N][32])
    unsigned short* h1  = hW + (size_t)R * N * 64;         // [N][64] bf16
    unsigned short* Wt1 = h1 + (size_t)N * 64;             // [(R+1)*64*64]
    unsigned short* Wt2 = Wt1 + (size_t)(R + 1) * 64 * 64; // [(R+1)*32*64]
    int*   gcnt  = (int*)(Wt2 + (size_t)(R + 1) * 32 * 64);    // [B]
    int*   rs    = gcnt + B;                               // [N]
    int*   re_   = rs + N;                                 // [N]
    int*   rec   = re_ + N;                                // [B*MAXPB]
    int*   eidx  = rec + (size_t)B * MAXPB;                // [B*MAXPB]

    const dim3 blk(256);
    const int nblk64 = (N + 63) / 64;
    const int P  = 512;                       // partition blocks
    const int CH = (E + P - 1) / P;           // 3125 edges per block

    // ---- Weight pre-transpose (bf16, [r][h][d]) ----
    transpose_w<64><<<((R + 1) * 64 * 64 + 255) / 256, blk, 0, stream>>>(W1, Ws1, Wt1, R);
    transpose_w<32><<<((R + 1) * 32 * 64 + 255) / 256, blk, 0, stream>>>(W2, Ws2, Wt2, R);

    // ---- Build per-node CSR (padded buckets; no hist/scan kernels) ----
    zero_int<<<(B + 255) / 256, blk, 0, stream>>>(gcnt, B);
    partition_pad<<<P, blk, 0, stream>>>(src, dst, et, gcnt, rec, E, N, B, CH);
    bucket_sort<<<B, blk, 0, stream>>>(gcnt, rec, eidx, rs, re_, N);

    // ---- Layer 1 ---- (hW1 bf16 + self-loop bf16 into h1, fused)
    if (R == 8)
        gemm_rel_mfma<64, 8, false, true><<<nblk64, 512, 0, stream>>>(feat, Wt1, b1, hW, h1, N, R, 0);
    else
        gemm_rel_mfma<64, 0, false, true><<<nblk64, 512, 0, stream>>>(feat, Wt1, b1, hW, h1, N, R, 0);
    agg_csr64<<<dim3((N + 3) / 4), blk, 0, stream>>>((const unsigned int*)hW, rs, re_, eidx,
                                                     (unsigned int*)h1, N);

    // ---- Layer 2 ---- (bf16 A staging with bit-mask ReLU; self fp32 -> out)
    if (R == 8)
        gemm_rel_mfma<32, 8, true, false><<<nblk64, 512, 0, stream>>>(h1, Wt2, b2, hW, out, N, R, 1);
    else
        gemm_rel_mfma<32, 0, true, false><<<nblk64, 512, 0, stream>>>(h1, Wt2, b2, hW, out, N, R, 1);
    agg_csr32<<<dim3((N + 7) / 8), blk, 0, stream>>>((const unsigned int*)hW, rs, re_, eidx, out, N);
}

// Round 12
// 319.793 us; speedup vs baseline: 1.2970x; 1.0543x over previous
//
#include <hip/hip_runtime.h>
#include <hip/hip_bf16.h>

typedef __attribute__((ext_vector_type(8))) short short8;
typedef __attribute__((ext_vector_type(4))) float f32x4;

__device__ __forceinline__ unsigned short f2bf(float v) {
    __hip_bfloat16 h = __float2bfloat16(v);   // RNE
    return *reinterpret_cast<unsigned short*>(&h);
}
__device__ __forceinline__ float bf2f(unsigned short u) {
    union { unsigned int i; float f; } x;
    x.i = (unsigned int)u << 16;
    return x.f;
}
__device__ __forceinline__ void acc4(float& s0, float& s1, float& s2, float& s3, uint2 v) {
    s0 += bf2f((unsigned short)(v.x & 0xffff));
    s1 += bf2f((unsigned short)(v.x >> 16));
    s2 += bf2f((unsigned short)(v.y & 0xffff));
    s3 += bf2f((unsigned short)(v.y >> 16));
}

// Cross-wave LDS barrier WITHOUT the vmcnt(0) drain __syncthreads carries.
__device__ __forceinline__ void lds_barrier() {
    asm volatile("s_waitcnt lgkmcnt(0)" ::: "memory");
    __builtin_amdgcn_s_barrier();
    asm volatile("" ::: "memory");
}

constexpr int MAXB  = 2048;   // max fine buckets (N/64 = 1563 here)
constexpr int MAXPB = 1792;   // padded slots per bucket (mean 1024, sigma 32 -> 24 sigma)
constexpr int SMEM  = 64 * 72 * 2 + 2 * 64 * 36 * 4;   // 27648 B (gemm As + dbuf Csf)

// ---------------------------------------------------------------------------
// Merged weight pre-transpose: Wt[(r*H + h)*64 + d] for both layers.
// ---------------------------------------------------------------------------
__global__ __launch_bounds__(256) void transpose_both(
    const float* __restrict__ W1, const float* __restrict__ Ws1,
    const float* __restrict__ W2, const float* __restrict__ Ws2,
    unsigned short* __restrict__ Wt1, unsigned short* __restrict__ Wt2, int R)
{
    int i = blockIdx.x * 256 + threadIdx.x;
    int t1 = (R + 1) * 64 * 64;
    int t2 = (R + 1) * 32 * 64;
    if (i < t1) {
        int d = i & 63, hh = i >> 6;
        int r = hh >> 6, h = hh & 63;
        float v = (r < R) ? W1[((size_t)r * 64 + d) * 64 + h] : Ws1[(size_t)d * 64 + h];
        Wt1[i] = f2bf(v);
    } else if (i < t1 + t2) {
        int j = i - t1;
        int d = j & 63, hh = j >> 6;
        int r = hh >> 5, h = hh & 31;
        float v = (r < R) ? W2[((size_t)r * 64 + d) * 32 + h] : Ws2[(size_t)d * 32 + h];
        Wt2[j] = f2bf(v);
    }
}

// ---------------------------------------------------------------------------
// Padded bucket partition body (512 threads; R8/R11-verified logic).
// Record: (et*N + src) << 6 | (dst & 63).
// ---------------------------------------------------------------------------
__device__ __forceinline__ void partition_body(
    char* smem, const int* __restrict__ src, const int* __restrict__ dst,
    const int* __restrict__ et, int* __restrict__ gcnt,
    int* __restrict__ rec, int E, int N, int B, int CH, int bidx)
{
    int* cnt  = (int*)smem;                       // MAXB ints
    int* base = (int*)(smem + sizeof(int) * MAXB);
    const int t = threadIdx.x;                    // 0..511
    const int e0 = bidx * CH, e1 = min(E, e0 + CH);

    for (int i = t; i < B; i += 512) cnt[i] = 0;
    __syncthreads();
    for (int e = e0 + t; e < e1; e += 512) atomicAdd(&cnt[dst[e] >> 6], 1);
    __syncthreads();
    for (int i = t; i < B; i += 512) {
        int h = cnt[i];
        base[i] = h ? atomicAdd(&gcnt[i], h) : 0;
        cnt[i] = 0;
    }
    __syncthreads();
    for (int e = e0 + t; e < e1; e += 512) {
        int d = dst[e];
        int b = d >> 6;
        int pos = base[b] + atomicAdd(&cnt[b], 1);
        if (pos < MAXPB)
            rec[(size_t)b * MAXPB + pos] = ((et[e] * N + src[e]) << 6) | (d & 63);
    }
}

// ---------------------------------------------------------------------------
// MFMA relation GEMM body (operand-swapped, depth-2 W prefetch, dbuf LDS
// epilogue with lgkm-only barriers). Verbatim R11 logic over aliased smem.
// ---------------------------------------------------------------------------
template<int H, int RT, bool ABF, bool SBF>
__device__ __forceinline__ void gemm_body(
    char* smem, const void* __restrict__ Av, const unsigned short* __restrict__ Wt,
    const float* __restrict__ bias,
    unsigned short* __restrict__ C, void* __restrict__ Cselfv,
    int N, int Rrt, int relu, int bidx)
{
    constexpr int AS = 72;   // 144 B/row = 36 words = 4 mod 32 -> 2-way (free)
    constexpr int CPB = (H == 64) ? 72 : 40;   // bf16 staging stride (16B-aligned rows)
    unsigned short* As = (unsigned short*)smem;             // 9216 B
    float* CsfBase = (float*)(smem + 64 * AS * 2);          // 2 x 9216 B
    const int R = RT ? RT : Rrt;
    const int tid = threadIdx.x;
    const int n0 = bidx * 64;

    if constexpr (ABF) {
        const unsigned short* A = (const unsigned short*)Av;
        int n = tid >> 3, d8 = (tid & 7) * 8;
        int gn = n0 + n;
        short8 u = {};
        if (gn < N) u = *(const short8*)&A[(size_t)gn * 64 + d8];
        if (relu) {
            #pragma unroll
            for (int j = 0; j < 8; ++j) {
                unsigned short x = (unsigned short)u[j];
                u[j] = (short)((x & 0x8000) ? 0 : x);   // bf16 relu = sign test
            }
        }
        *(short8*)&As[n * AS + d8] = u;
    } else {
        const float* A = (const float*)Av;
        #pragma unroll
        for (int i = 0; i < 2; ++i) {
            int lin = tid + i * 512;
            int n = lin >> 4;
            int d4 = (lin & 15) * 4;
            int gn = n0 + n;
            float4 v = make_float4(0.f, 0.f, 0.f, 0.f);
            if (gn < N) v = *(const float4*)&A[(size_t)gn * 64 + d4];
            if (relu) {
                v.x = fmaxf(v.x, 0.f); v.y = fmaxf(v.y, 0.f);
                v.z = fmaxf(v.z, 0.f); v.w = fmaxf(v.w, 0.f);
            }
            ushort4 u;
            u.x = f2bf(v.x); u.y = f2bf(v.y); u.z = f2bf(v.z); u.w = f2bf(v.w);
            *(ushort4*)&As[n * AS + d4] = u;
        }
    }

    const int w = tid >> 6, lane = tid & 63;
    const int m = lane & 15, quad = lane >> 4;
    const int wt = w & 3;        // node sub-tile (16 nodes)
    const int half = w >> 2;     // column half (H/2 cols)

    lds_barrier();

    short8 afrag[2];
    afrag[0] = *(const short8*)&As[(wt * 16 + m) * AS + 0 * 32 + quad * 8];
    afrag[1] = *(const short8*)&As[(wt * 16 + m) * AS + 1 * 32 + quad * 8];

    constexpr int NT = H / 32;   // col-tiles per wave (64->2, 32->1)

    auto wptr = [&](int r, int nt, int kc) {
        int colbase = half * (H / 2) + nt * 16;
        return (const short8*)&Wt[((size_t)(r * H + colbase + m)) * 64 + kc * 32 + quad * 8];
    };

    short8 wf0[NT][2], wf1[NT][2];
    #pragma unroll
    for (int nt = 0; nt < NT; ++nt) { wf0[nt][0] = *wptr(0, nt, 0); wf0[nt][1] = *wptr(0, nt, 1); }
    #pragma unroll
    for (int nt = 0; nt < NT; ++nt) { wf1[nt][0] = *wptr(1, nt, 0); wf1[nt][1] = *wptr(1, nt, 1); }

    #pragma unroll
    for (int r = 0; r <= R; ++r) {
        short8 wn[NT][2];
        if (r + 2 <= R) {
            #pragma unroll
            for (int nt = 0; nt < NT; ++nt) {
                wn[nt][0] = *wptr(r + 2, nt, 0);
                wn[nt][1] = *wptr(r + 2, nt, 1);
            }
        }

        f32x4 acc[NT];
        #pragma unroll
        for (int nt = 0; nt < NT; ++nt) {
            acc[nt] = (f32x4){0.f, 0.f, 0.f, 0.f};
            acc[nt] = __builtin_amdgcn_mfma_f32_16x16x32_bf16(wf0[nt][0], afrag[0], acc[nt], 0, 0, 0);
            acc[nt] = __builtin_amdgcn_mfma_f32_16x16x32_bf16(wf0[nt][1], afrag[1], acc[nt], 0, 0, 0);
        }

        // ---- stage into Csf[r&1] ----
        float* Cf = CsfBase + (r & 1) * (64 * 36);
        unsigned short* Cb = (unsigned short*)Cf;
        if (r < R) {
            #pragma unroll
            for (int nt = 0; nt < NT; ++nt) {
                int col = half * (H / 2) + nt * 16 + quad * 4;
                ushort4 u;
                u.x = f2bf(acc[nt][0]); u.y = f2bf(acc[nt][1]);
                u.z = f2bf(acc[nt][2]); u.w = f2bf(acc[nt][3]);
                *(ushort4*)&Cb[(wt * 16 + m) * CPB + col] = u;
            }
        } else if constexpr (SBF) {
            #pragma unroll
            for (int nt = 0; nt < NT; ++nt) {
                int col = half * (H / 2) + nt * 16 + quad * 4;
                const float4 bv = *(const float4*)&bias[col];
                ushort4 u;
                u.x = f2bf(acc[nt][0] + bv.x); u.y = f2bf(acc[nt][1] + bv.y);
                u.z = f2bf(acc[nt][2] + bv.z); u.w = f2bf(acc[nt][3] + bv.w);
                *(ushort4*)&Cb[(wt * 16 + m) * CPB + col] = u;
            }
        } else {
            #pragma unroll
            for (int nt = 0; nt < NT; ++nt) {
                int col = half * (H / 2) + nt * 16 + quad * 4;
                const float4 bv = *(const float4*)&bias[col];
                float4 o = make_float4(acc[nt][0] + bv.x, acc[nt][1] + bv.y,
                                       acc[nt][2] + bv.z, acc[nt][3] + bv.w);
                *(float4*)&Cf[(wt * 16 + m) * 36 + col] = o;
            }
        }

        lds_barrier();   // lgkm-only: stage(r) visible; r-1 readout reads done

        // ---- coalesced readout from Csf[r&1] ----
        if (r < R) {
            if (H == 64) {
                int rw = tid >> 3, ch = tid & 7;      // 64 rows x 8 chunks of 16B
                int gn = n0 + rw;
                if (gn < N) {
                    uint4 v = *(const uint4*)&Cb[rw * CPB + ch * 8];
                    *(uint4*)&C[((size_t)r * N + gn) * H + ch * 8] = v;
                }
            } else {
                if (tid < 256) {
                    int rw = tid >> 2, ch = tid & 3;  // 64 rows x 4 chunks of 16B
                    int gn = n0 + rw;
                    if (gn < N) {
                        uint4 v = *(const uint4*)&Cb[rw * CPB + ch * 8];
                        *(uint4*)&C[((size_t)r * N + gn) * H + ch * 8] = v;
                    }
                }
            }
        } else if constexpr (SBF) {
            unsigned short* Cs = (unsigned short*)Cselfv;
            int rw = tid >> 3, ch = tid & 7;
            int gn = n0 + rw;
            if (gn < N) {
                uint4 v = *(const uint4*)&Cb[rw * CPB + ch * 8];
                *(uint4*)&Cs[(size_t)gn * H + ch * 8] = v;
            }
        } else {
            float* outf = (float*)Cselfv;
            int rw = tid >> 3, ch = tid & 7;          // 64 rows x 8 float4
            int gn = n0 + rw;
            if (gn < N) {
                float4 v = *(const float4*)&Cf[rw * 36 + ch * 4];
                *(float4*)&outf[(size_t)gn * 32 + ch * 4] = v;
            }
        }

        #pragma unroll
        for (int nt = 0; nt < NT; ++nt) {
            wf0[nt][0] = wf1[nt][0]; wf0[nt][1] = wf1[nt][1];
            wf1[nt][0] = wn[nt][0];  wf1[nt][1] = wn[nt][1];
        }
    }
}

// ---------------------------------------------------------------------------
// MEGA kernel: blocks [0,P) run the edge partition; blocks [P,..) run the
// layer-1 gemm. Independent work overlapped in one dispatch.
// ---------------------------------------------------------------------------
template<int RT>
__global__ __launch_bounds__(512) void mega64(
    const float* __restrict__ feat, const unsigned short* __restrict__ Wt1,
    const float* __restrict__ b1, unsigned short* __restrict__ hW,
    unsigned short* __restrict__ h1,
    const int* __restrict__ src, const int* __restrict__ dst,
    const int* __restrict__ et, int* __restrict__ gcnt, int* __restrict__ rec,
    int E, int N, int B, int CH, int P, int R)
{
    __shared__ alignas(16) char smem[SMEM];
    if ((int)blockIdx.x < P) {
        partition_body(smem, src, dst, et, gcnt, rec, E, N, B, CH, blockIdx.x);
    } else {
        gemm_body<64, RT, false, true>(smem, feat, Wt1, b1, hW, h1, N, R, 0,
                                       blockIdx.x - P);
    }
}

// Layer-2 gemm wrapper (unchanged semantics).
template<int H, int RT, bool ABF, bool SBF>
__global__ __launch_bounds__(512) void gemm_rel_mfma(
    const void* __restrict__ Av, const unsigned short* __restrict__ Wt,
    const float* __restrict__ bias,
    unsigned short* __restrict__ C, void* __restrict__ Cselfv,
    int N, int Rrt, int relu)
{
    __shared__ alignas(16) char smem[SMEM];
    gemm_body<H, RT, ABF, SBF>(smem, Av, Wt, bias, C, Cselfv, N, Rrt, relu, blockIdx.x);
}

// ---------------------------------------------------------------------------
// Per-bucket counting sort -> per-node ranges rs/re into padded eidx.
// ---------------------------------------------------------------------------
__global__ __launch_bounds__(256) void bucket_sort(
    const int* __restrict__ gcnt, const int* __restrict__ rec,
    int* __restrict__ eidx, int* __restrict__ rs, int* __restrict__ re_,
    int N)
{
    __shared__ int hist[64];
    __shared__ int excl[64];
    __shared__ int cur[64];
    const int b = blockIdx.x;
    const int tid = threadIdx.x;
    const int p0 = b * MAXPB;
    const int ne = min(gcnt[b], MAXPB);

    if (tid < 64) hist[tid] = 0;
    __syncthreads();
    for (int p = tid; p < ne; p += 256)
        atomicAdd(&hist[rec[p0 + p] & 63], 1);
    __syncthreads();
    if (tid == 0) {
        int run = 0;
        #pragma unroll
        for (int i = 0; i < 64; ++i) { excl[i] = run; run += hist[i]; }
    }
    __syncthreads();
    if (tid < 64) {
        cur[tid] = excl[tid];
        int n = b * 64 + tid;
        if (n < N) {
            rs[n]  = p0 + excl[tid];
            re_[n] = p0 + excl[tid] + hist[tid];
        }
    }
    __syncthreads();
    for (int p = tid; p < ne; p += 256) {
        int rv = rec[p0 + p];
        int pos = p0 + atomicAdd(&cur[rv & 63], 1);
        eidx[pos] = rv >> 6;   // et*N + src
    }
}

// ---------------------------------------------------------------------------
// agg64 v2 (R11-verified): one wave per dst node; 4 groups of 16 lanes, uint2
// row loads, 4-deep unroll; shfl_xor(16,32) combine; group 0 RMW of h1.
// ---------------------------------------------------------------------------
__global__ __launch_bounds__(256) void agg_csr64(
    const unsigned int* __restrict__ hw32, const int* __restrict__ rs,
    const int* __restrict__ re_, const int* __restrict__ eidx,
    unsigned int* __restrict__ out32, int N)
{
    const int d = blockIdx.x * 4 + (threadIdx.x >> 6);
    const int lane = threadIdx.x & 63;
    if (d >= N) return;
    const int g = lane >> 4;      // edge group 0..3
    const int c = lane & 15;      // uint2 col (4 bf16 cols: 4c..4c+3)
    const int p0 = rs[d], p1 = re_[d];
    float s0 = 0.f, s1 = 0.f, s2 = 0.f, s3 = 0.f;
    int p = p0 + g;
    for (; p + 12 < p1; p += 16) {
        uint2 v0 = *(const uint2*)&hw32[(size_t)eidx[p]      * 32 + 2 * c];
        uint2 v1 = *(const uint2*)&hw32[(size_t)eidx[p + 4]  * 32 + 2 * c];
        uint2 v2 = *(const uint2*)&hw32[(size_t)eidx[p + 8]  * 32 + 2 * c];
        uint2 v3 = *(const uint2*)&hw32[(size_t)eidx[p + 12] * 32 + 2 * c];
        acc4(s0, s1, s2, s3, v0);
        acc4(s0, s1, s2, s3, v1);
        acc4(s0, s1, s2, s3, v2);
        acc4(s0, s1, s2, s3, v3);
    }
    for (; p < p1; p += 4) {
        uint2 v = *(const uint2*)&hw32[(size_t)eidx[p] * 32 + 2 * c];
        acc4(s0, s1, s2, s3, v);
    }
    s0 += __shfl_xor(s0, 16, 64); s1 += __shfl_xor(s1, 16, 64);
    s2 += __shfl_xor(s2, 16, 64); s3 += __shfl_xor(s3, 16, 64);
    s0 += __shfl_xor(s0, 32, 64); s1 += __shfl_xor(s1, 32, 64);
    s2 += __shfl_xor(s2, 32, 64); s3 += __shfl_xor(s3, 32, 64);
    if (g == 0) {
        uint2 cur = *(const uint2*)&out32[(size_t)d * 32 + 2 * c];
        float o0 = s0 + bf2f((unsigned short)(cur.x & 0xffff));
        float o1 = s1 + bf2f((unsigned short)(cur.x >> 16));
        float o2 = s2 + bf2f((unsigned short)(cur.y & 0xffff));
        float o3 = s3 + bf2f((unsigned short)(cur.y >> 16));
        uint2 o;
        o.x = (unsigned int)f2bf(o0) | ((unsigned int)f2bf(o1) << 16);
        o.y = (unsigned int)f2bf(o2) | ((unsigned int)f2bf(o3) << 16);
        *(uint2*)&out32[(size_t)d * 32 + 2 * c] = o;
    }
}

// ---------------------------------------------------------------------------
// agg32 v2 (R11-verified): 32 lanes per dst node; 4 groups of 8 lanes, uint2
// row loads, 4-deep unroll; shfl_xor(8,16) combine; group 0 float4 RMW of out.
// ---------------------------------------------------------------------------
__global__ __launch_bounds__(256) void agg_csr32(
    const unsigned int* __restrict__ hw32, const int* __restrict__ rs,
    const int* __restrict__ re_, const int* __restrict__ eidx,
    float* __restrict__ out, int N)
{
    const int d = blockIdx.x * 8 + (threadIdx.x >> 5);
    const int l = threadIdx.x & 31;
    if (d >= N) return;
    const int g = l >> 3;         // edge group 0..3
    const int c = l & 7;          // uint2 col (4 bf16 cols of 32)
    const int p0 = rs[d], p1 = re_[d];
    float s0 = 0.f, s1 = 0.f, s2 = 0.f, s3 = 0.f;
    int p = p0 + g;
    for (; p + 12 < p1; p += 16) {
        uint2 v0 = *(const uint2*)&hw32[(size_t)eidx[p]      * 16 + 2 * c];
        uint2 v1 = *(const uint2*)&hw32[(size_t)eidx[p + 4]  * 16 + 2 * c];
        uint2 v2 = *(const uint2*)&hw32[(size_t)eidx[p + 8]  * 16 + 2 * c];
        uint2 v3 = *(const uint2*)&hw32[(size_t)eidx[p + 12] * 16 + 2 * c];
        acc4(s0, s1, s2, s3, v0);
        acc4(s0, s1, s2, s3, v1);
        acc4(s0, s1, s2, s3, v2);
        acc4(s0, s1, s2, s3, v3);
    }
    for (; p < p1; p += 4) {
        uint2 v = *(const uint2*)&hw32[(size_t)eidx[p] * 16 + 2 * c];
        acc4(s0, s1, s2, s3, v);
    }
    s0 += __shfl_xor(s0, 8, 64);  s1 += __shfl_xor(s1, 8, 64);
    s2 += __shfl_xor(s2, 8, 64);  s3 += __shfl_xor(s3, 8, 64);
    s0 += __shfl_xor(s0, 16, 64); s1 += __shfl_xor(s1, 16, 64);
    s2 += __shfl_xor(s2, 16, 64); s3 += __shfl_xor(s3, 16, 64);
    if (g == 0) {
        float4 cur = *(const float4*)&out[(size_t)d * 32 + 4 * c];
        float4 o = make_float4(cur.x + s0, cur.y + s1, cur.z + s2, cur.w + s3);
        *(float4*)&out[(size_t)d * 32 + 4 * c] = o;
    }
}

extern "C" void kernel_launch(void* const* d_in, const int* in_sizes, int n_in,
                              void* d_out, int out_size, void* d_ws, size_t ws_size,
                              hipStream_t stream)
{
    const float* feat = (const float*)d_in[0];
    const int*   src  = (const int*)d_in[1];
    const int*   dst  = (const int*)d_in[2];
    const int*   et   = (const int*)d_in[3];
    const float* W1   = (const float*)d_in[4];
    const float* Ws1  = (const float*)d_in[5];
    const float* b1   = (const float*)d_in[6];
    const float* W2   = (const float*)d_in[7];
    const float* Ws2  = (const float*)d_in[8];
    const float* b2   = (const float*)d_in[9];
    float* out = (float*)d_out;

    const int N = in_sizes[0] / 64;           // 100000
    const int E = in_sizes[1];                // 1600000
    const int R = in_sizes[4] / (64 * 64);    // 8
    const int B = (N + 63) / 64;              // 1563 fine buckets

    // Workspace layout
    unsigned short* hW  = (unsigned short*)d_ws;           // [R][N][64] bf16 (reused [R][N][32])
    unsigned short* h1  = hW + (size_t)R * N * 64;         // [N][64] bf16
    unsigned short* Wt1 = h1 + (size_t)N * 64;             // [(R+1)*64*64]
    unsigned short* Wt2 = Wt1 + (size_t)(R + 1) * 64 * 64; // [(R+1)*32*64]
    int*   gcnt  = (int*)(Wt2 + (size_t)(R + 1) * 32 * 64);    // [B]
    int*   rs    = gcnt + B;                               // [N]
    int*   re_   = rs + N;                                 // [N]
    int*   rec   = re_ + N;                                // [B*MAXPB]
    int*   eidx  = rec + (size_t)B * MAXPB;                // [B*MAXPB]

    const dim3 blk(256);
    const int nblk64 = (N + 63) / 64;
    const int P  = 512;                       // partition blocks
    const int CH = (E + P - 1) / P;           // 3125 edges per block

    // ---- gcnt zero (memset, capture-safe) + merged weight pre-transpose ----
    hipMemsetAsync(gcnt, 0, (size_t)B * sizeof(int), stream);
    {
        int total = (R + 1) * 96 * 64;
        transpose_both<<<(total + 255) / 256, blk, 0, stream>>>(W1, Ws1, W2, Ws2, Wt1, Wt2, R);
    }

    // ---- MEGA: edge partition (blocks 0..P-1) || layer-1 gemm (rest) ----
    if (R == 8)
        mega64<8><<<P + nblk64, 512, 0, stream>>>(feat, Wt1, b1, hW, h1,
                                                  src, dst, et, gcnt, rec,
                                                  E, N, B, CH, P, R);
    else
        mega64<0><<<P + nblk64, 512, 0, stream>>>(feat, Wt1, b1, hW, h1,
                                                  src, dst, et, gcnt, rec,
                                                  E, N, B, CH, P, R);

    // ---- Per-bucket sort -> per-node CSR ----
    bucket_sort<<<B, blk, 0, stream>>>(gcnt, rec, eidx, rs, re_, N);

    // ---- Layer 1 aggregation ----
    agg_csr64<<<dim3((N + 3) / 4), blk, 0, stream>>>((const unsigned int*)hW, rs, re_, eidx,
                                                     (unsigned int*)h1, N);

    // ---- Layer 2 ---- (bf16 A staging with bit-mask ReLU; self fp32 -> out)
    if (R == 8)
        gemm_rel_mfma<32, 8, true, false><<<nblk64, 512, 0, stream>>>(h1, Wt2, b2, hW, out, N, R, 1);
    else
        gemm_rel_mfma<32, 0, true, false><<<nblk64, 512, 0, stream>>>(h1, Wt2, b2, hW, out, N, R, 1);
    agg_csr32<<<dim3((N + 7) / 8), blk, 0, stream>>>((const unsigned int*)hW, rs, re_, eidx, out, N);
}